// Round 10
// baseline (167.531 us; speedup 1.0000x reference)
//
#include <hip/hip_runtime.h>
#include <hip/hip_bf16.h>
#include <stdint.h>

#define BB 32
#define IC 128
#define OC 128
#define HH 56
#define WW 56
#define ZD 512
#define NRS 9
#define OI (OC*IC)            // 16384
#define WROWS (OI*NRS)        // 147456
#define NHEADBLK 1024         // 144 rows each (16 oi x 9 rs)
#define NTRBLK (HH * BB)      // 1792
#define XP 58                 // padded spatial dim
#define XROW (XP * IC)        // shorts per padded row (7424)
#define XBAT ((size_t)XP * XP * IC)  // shorts per padded sample (430592)

typedef float  f32x4  __attribute__((ext_vector_type(4)));
typedef short  bf16x8 __attribute__((ext_vector_type(8)));
typedef short  s16x4  __attribute__((ext_vector_type(4)));

static __device__ __forceinline__ short f2bf(float f) {
    uint32_t u = __float_as_uint(f);
    uint32_t r = (u + 0x7fffu + ((u >> 16) & 1u)) >> 16;
    return (short)r;
}
static __device__ __forceinline__ short f2bf_hw(float f) {
    __hip_bfloat16 h = __float2bfloat16(f);
    return *reinterpret_cast<short*>(&h);
}
static __device__ __forceinline__ float bf2f(short s) {
    uint32_t u = ((uint32_t)(uint16_t)s) << 16;
    return __uint_as_float(u);
}

// ---------------------------------------------------------------------------
// Kernel 1 (v9): FUSED head + in-block repack + PADDED transpose.
// Head blocks (0..1023): unchanged from round 9 (at the ~2.75 TB/s pure-read
// cap; six structural variants all pinned there).
// Transpose blocks: x NCHW fp32 -> xtp[b][v=h+1][u=w+1][ic] bf16 with zero
// halo rows/cols, so conv can read B-fragments directly from global.
// ---------------------------------------------------------------------------
__global__ __launch_bounds__(576, 1) void fused_head_tr_kernel(
    const float* __restrict__ Wh, const float* __restrict__ z,
    const float* __restrict__ bh, short* __restrict__ wbf,
    const float* __restrict__ x, short* __restrict__ xtp)
{
    if (blockIdx.x >= NHEADBLK) {
        // ---------------- padded transpose part ----------------
        const int bx = blockIdx.x - NHEADBLK;
        const int b = bx / HH;
        const int h = bx - b * HH;
        const int tid = threadIdx.x;
        short* xb = xtp + (size_t)b * XBAT;

        if (tid < 512) {
            const int w = tid & 63;
            const int yq = tid >> 6;           // 0..7
            if (w < WW) {
                const float* xp = x + (size_t)b * IC * HH * WW + h * WW + w;
                short* op = xb + ((size_t)(h + 1) * XP + (w + 1)) * IC;
                #pragma unroll
                for (int q = 0; q < 2; ++q) {
                    int ic = yq * 2 + q;       // 0..15
                    bf16x8 pk;
                    #pragma unroll
                    for (int j = 0; j < 8; ++j) {
                        float v = xp[(size_t)(ic * 8 + j) * (HH * WW)];
                        pk[j] = f2bf(v);
                    }
                    *(bf16x8*)(op + ic * 8) = pk;
                }
            }
        } else if (tid < 544) {
            // zero halo cols u=0 and u=57 of row v=h+1 (2 x 256 B)
            int t = tid - 512;
            int u = (t >> 4) * (XP - 1);
            *(f32x4*)((char*)(xb + ((size_t)(h + 1) * XP + u) * IC) + (t & 15) * 16) =
                (f32x4){0.f, 0.f, 0.f, 0.f};
        }
        // zero halo rows v=0 (by h==0 block) and v=57 (by h==55 block)
        if (h == 0 || h == HH - 1) {
            const int v = (h == 0) ? 0 : XP - 1;
            char* rowp = (char*)(xb + (size_t)v * XROW);
            for (int idx = tid; idx < XROW * 2 / 16; idx += 576)
                *(f32x4*)(rowp + idx * 16) = (f32x4){0.f, 0.f, 0.f, 0.f};
        }
        return;
    }

    // ---------------- head part (unchanged) ----------------
    __shared__ __align__(16) char Zl[32 * 1024];   // z bf16 swizzled, 32 KB
    __shared__ __align__(16) char Sl[144 * 64];    // result staging, 9216 B
    const int tid  = threadIdx.x;
    const int lane = tid & 63;
    const int wv   = tid >> 6;                     // 0..8

    if (tid < 256) {
        const int b = tid >> 3, ks = (tid & 7) * 64;
        const float* zp = z + (size_t)b * ZD + ks;
        const int bx = (b & 7) << 4;
        #pragma unroll
        for (int j8 = 0; j8 < 8; ++j8) {
            f32x4 v0 = *(const f32x4*)(zp + j8 * 8);
            f32x4 v1 = *(const f32x4*)(zp + j8 * 8 + 4);
            bf16x8 pk;
            pk[0] = f2bf_hw(v0.x); pk[1] = f2bf_hw(v0.y);
            pk[2] = f2bf_hw(v0.z); pk[3] = f2bf_hw(v0.w);
            pk[4] = f2bf_hw(v1.x); pk[5] = f2bf_hw(v1.y);
            pk[6] = f2bf_hw(v1.z); pk[7] = f2bf_hw(v1.w);
            *(bf16x8*)(Zl + b * 1024 + ((ks * 2 + j8 * 16) ^ bx)) = pk;
        }
    }
    __syncthreads();   // Zl ready

    const int rl = lane & 15;
    const int kq = lane >> 4;
    const int zxor = (rl & 7) << 4;
    const int rowLocal = wv * 16 + rl;   // 0..143
    const int rowg = blockIdx.x * 144 + rowLocal;

    const char* wp = (const char*)Wh + (size_t)rowg * (ZD * 4) + kq * 32;

    f32x4 wd[16];
    #pragma unroll
    for (int i = 0; i < 8; ++i) {
        wd[2 * i]     = *(const f32x4*)(wp + i * 128);
        wd[2 * i + 1] = *(const f32x4*)(wp + i * 128 + 16);
    }

    f32x4 acc0 = {0.f, 0.f, 0.f, 0.f}, acc1 = {0.f, 0.f, 0.f, 0.f};
    #pragma unroll
    for (int kb = 0; kb < 16; ++kb) {
        const int sl = kb & 7;
        const int koff = (kb * 64 + kq * 16) ^ zxor;
        bf16x8 a0 = *(const bf16x8*)(Zl + rl * 1024 + koff);
        bf16x8 a1 = *(const bf16x8*)(Zl + (16 + rl) * 1024 + koff);
        f32x4 lo = wd[2 * sl];
        f32x4 hi = wd[2 * sl + 1];
        bf16x8 bw;
        bw[0] = f2bf_hw(lo.x); bw[1] = f2bf_hw(lo.y);
        bw[2] = f2bf_hw(lo.z); bw[3] = f2bf_hw(lo.w);
        bw[4] = f2bf_hw(hi.x); bw[5] = f2bf_hw(hi.y);
        bw[6] = f2bf_hw(hi.z); bw[7] = f2bf_hw(hi.w);
        acc0 = __builtin_amdgcn_mfma_f32_16x16x32_bf16(a0, bw, acc0, 0, 0, 0);
        acc1 = __builtin_amdgcn_mfma_f32_16x16x32_bf16(a1, bw, acc1, 0, 0, 0);
        if (kb < 8) {
            wd[2 * sl]     = *(const f32x4*)(wp + (kb + 8) * 128);
            wd[2 * sl + 1] = *(const f32x4*)(wp + (kb + 8) * 128 + 16);
        }
    }

    {
        const int swz = (rowLocal & 7) << 3;
        s16x4 s0, s1;
        #pragma unroll
        for (int reg = 0; reg < 4; ++reg) {
            s0[reg] = f2bf(acc0[reg]);
            s1[reg] = f2bf(acc1[reg]);
        }
        *(s16x4*)(Sl + rowLocal * 64 + ((kq * 8) ^ swz))      = s0;
        *(s16x4*)(Sl + rowLocal * 64 + ((32 + kq * 8) ^ swz)) = s1;
    }
    __syncthreads();

    if (tid < 512) {
        const int b  = tid >> 4;
        const int oiL = tid & 15;
        const int oi = blockIdx.x * 16 + oiL;
        #pragma unroll
        for (int rs = 0; rs < 9; ++rs) {
            const int rowL = oiL * 9 + rs;
            short sh = *(const short*)(Sl + rowL * 64 +
                                       ((2 * b) ^ ((rowL & 7) << 3)));
            float v = bf2f(sh) + bh[(size_t)oi * 9 + rs];
            wbf[((size_t)(b * 9 + rs)) * OI + oi] = f2bf(v);
        }
    }
}

// ---------------------------------------------------------------------------
// Kernel 3 (v4): conv with split operand paths.
// W (A-operand): reg-staged dbuf LDS (64 KB only -> 2 blocks/CU, 8 waves/CU),
// 2 barriers/rs, compiler-managed waits.  X (B-operand): direct global
// B-fragment loads from padded xtp (L1/L2-served, ~10x reuse).  4 waves,
// wave=(hh, og-half), 4x4 frags, BH=2.  XCD-bijective block remap keeps each
// b's 28 blocks on one XCD (wbf[b]+xtp[b] ~1.1 MB L2-resident).
// ---------------------------------------------------------------------------
__global__ __launch_bounds__(256) void conv_kernel(
    const short* __restrict__ wbf,   // [b][rs][o][i] bf16
    const short* __restrict__ xtp,   // [b][58][58][i] bf16, zero halo
    float* __restrict__ out)         // [b][o][h][w]  fp32
{
    __shared__ __align__(16) char Wl[2][32768];
    const int tid  = threadIdx.x;
    const int lane = tid & 63;
    const int wv   = tid >> 6;       // 0..3
    const int og   = wv & 1;         // o-half (64 o)
    const int hh   = wv >> 1;        // output row within block

    // bijective XCD remap: 896 blocks, 112 per XCD -> 4 consecutive b per XCD
    const int bid = blockIdx.x;
    const int wg  = (bid & 7) * 112 + (bid >> 3);
    const int b   = wg / 28;
    const int h0  = (wg - b * 28) * 2;

    const short* xb = xtp + (size_t)b * XBAT;
    const int rl = lane & 15;
    const int kq = lane >> 4;

    // ---- W staging (reg-staged, dbuf) ----
    f32x4 wr[8];
    #define WLOAD(rs_)                                                          \
        {                                                                       \
            const char* ws_ = (const char*)(wbf + ((size_t)b * NRS + (rs_)) * OI); \
            _Pragma("unroll")                                                   \
            for (int it_ = 0; it_ < 8; ++it_) {                                 \
                int c_ = (wv * 8 + it_) * 64 + lane;                            \
                int so_ = (c_ * 16) ^ (((c_ >> 4) & 7) << 4);                   \
                wr[it_] = *(const f32x4*)(ws_ + so_);                           \
            }                                                                   \
        }
    #define WSTORE(buf_)                                                        \
        _Pragma("unroll")                                                       \
        for (int it_ = 0; it_ < 8; ++it_)                                       \
            *(f32x4*)(Wl[buf_] + (wv * 8 + it_) * 1024 + lane * 16) = wr[it_];

    WLOAD(0);
    WSTORE(0);
    __syncthreads();
    WLOAD(1);

    f32x4 acc[4][4];   // [af][pf]
    #pragma unroll
    for (int a = 0; a < 4; ++a)
        #pragma unroll
        for (int p = 0; p < 4; ++p) acc[a][p] = (f32x4){0.f, 0.f, 0.f, 0.f};

    const int axor = (lane & 7) << 4;
    int kkoff[4];
    #pragma unroll
    for (int kk = 0; kk < 4; ++kk) kkoff[kk] = kk * 64 + (kq << 4);

    for (int rs = 0; rs < 9; ++rs) {
        const int r = rs / 3, s = rs - 3 * r;
        const char* Wb = Wl[rs & 1];
        // B-frag row base: v = h0+hh+r (padded row index), u = pc + s
        const short* xrow = xb + (size_t)(h0 + hh + r) * XROW;
        int uoff[4];
        #pragma unroll
        for (int pf = 0; pf < 4; ++pf) {
            int p = pf * 16 + rl;
            int pc = p > 55 ? 55 : p;          // clamp garbage lanes
            uoff[pf] = (pc + s) * IC + kq * 8; // element offset
        }
        #pragma unroll
        for (int kk = 0; kk < 4; ++kk) {
            bf16x8 av[4];
            #pragma unroll
            for (int af = 0; af < 4; ++af)
                av[af] = *(const bf16x8*)(Wb + (og * 64 + af * 16 + rl) * 256 +
                                          (kkoff[kk] ^ axor));
            #pragma unroll
            for (int pf = 0; pf < 4; ++pf) {
                bf16x8 bv = *(const bf16x8*)(xrow + uoff[pf] + kk * 32);
                #pragma unroll
                for (int af = 0; af < 4; ++af)
                    acc[af][pf] = __builtin_amdgcn_mfma_f32_16x16x32_bf16(
                        av[af], bv, acc[af][pf], 0, 0, 0);
            }
        }
        __syncthreads();                 // all waves done reading Wl[rs&1]
        if (rs < 8) { WSTORE((rs & 1) ^ 1); }
        if (rs < 7) { WLOAD(rs + 2); }
        __syncthreads();                 // W(rs+1) visible
    }
    #undef WLOAD
    #undef WSTORE

    // epilogue: D col = lane&15 (=p), row = 4*kq+reg (=o offset)
    const int hO = h0 + hh;
    #pragma unroll
    for (int af = 0; af < 4; ++af) {
        int o0 = og * 64 + af * 16 + kq * 4;
        #pragma unroll
        for (int pf = 0; pf < 4; ++pf) {
            int p = pf * 16 + rl;
            if (p < WW) {
                #pragma unroll
                for (int reg = 0; reg < 4; ++reg) {
                    out[(((size_t)b * OC + (o0 + reg)) * HH + hO) * WW + p] = acc[af][pf][reg];
                }
            }
        }
    }
}

extern "C" void kernel_launch(void* const* d_in, const int* in_sizes, int n_in,
                              void* d_out, int out_size, void* d_ws, size_t ws_size,
                              hipStream_t stream) {
    const float* x  = (const float*)d_in[0];   // [32,128,56,56]
    const float* z  = (const float*)d_in[1];   // [32,512]
    const float* Wh = (const float*)d_in[2];   // [147456,512]
    const float* bh = (const float*)d_in[3];   // [147456]
    float* out = (float*)d_out;

    short* wbf = (short*)d_ws;                               // 9,437,184 B
    short* xtp = (short*)((char*)d_ws + 9437184);            // 27,557,888 B

    fused_head_tr_kernel<<<dim3(NHEADBLK + NTRBLK), 576, 0, stream>>>(Wh, z, bh, wbf, x, xtp);
    conv_kernel<<<dim3(28 * 32), 256, 0, stream>>>(wbf, xtp, out);
}

// Round 11
// 141.320 us; speedup vs baseline: 1.1855x; 1.1855x over previous
//
#include <hip/hip_runtime.h>
#include <hip/hip_bf16.h>
#include <stdint.h>

#define BB 32
#define IC 128
#define OC 128
#define HH 56
#define WW 56
#define ZD 512
#define NRS 9
#define OI (OC*IC)            // 16384
#define WROWS (OI*NRS)        // 147456
#define NHEADBLK 1024         // 144 rows each (16 oi x 9 rs)
#define NTRBLK (HH * BB)      // 1792
#define XP 58                 // padded spatial dim
#define XROW (XP * IC)        // shorts per padded row (7424)
#define XBAT ((size_t)XP * XP * IC)  // shorts per padded sample (430592)
#define WDIM 58               // conv LDS width index u = w_in+1, 0..57

typedef float  f32x4  __attribute__((ext_vector_type(4)));
typedef short  bf16x8 __attribute__((ext_vector_type(8)));
typedef short  s16x4  __attribute__((ext_vector_type(4)));

static __device__ __forceinline__ short f2bf(float f) {
    uint32_t u = __float_as_uint(f);
    uint32_t r = (u + 0x7fffu + ((u >> 16) & 1u)) >> 16;
    return (short)r;
}
static __device__ __forceinline__ short f2bf_hw(float f) {
    __hip_bfloat16 h = __float2bfloat16(f);
    return *reinterpret_cast<short*>(&h);
}
static __device__ __forceinline__ float bf2f(short s) {
    uint32_t u = ((uint32_t)(uint16_t)s) << 16;
    return __uint_as_float(u);
}
static __device__ __forceinline__ void gll16(const void* g, void* l) {
    __builtin_amdgcn_global_load_lds(
        (const __attribute__((address_space(1))) uint32_t*)g,
        (__attribute__((address_space(3))) uint32_t*)l, 16, 0, 0);
}

// ---------------------------------------------------------------------------
// Kernel 1 (v9/v10): FUSED head + in-block repack + PADDED transpose.
// Unchanged from round 10 (passed, absmax 1.0). Head at the ~2.75 TB/s
// pure-read cap (six structural variants pinned there).
// ---------------------------------------------------------------------------
__global__ __launch_bounds__(576, 1) void fused_head_tr_kernel(
    const float* __restrict__ Wh, const float* __restrict__ z,
    const float* __restrict__ bh, short* __restrict__ wbf,
    const float* __restrict__ x, short* __restrict__ xtp)
{
    if (blockIdx.x >= NHEADBLK) {
        // ---------------- padded transpose part ----------------
        const int bx = blockIdx.x - NHEADBLK;
        const int b = bx / HH;
        const int h = bx - b * HH;
        const int tid = threadIdx.x;
        short* xb = xtp + (size_t)b * XBAT;

        if (tid < 512) {
            const int w = tid & 63;
            const int yq = tid >> 6;           // 0..7
            if (w < WW) {
                const float* xp = x + (size_t)b * IC * HH * WW + h * WW + w;
                short* op = xb + ((size_t)(h + 1) * XP + (w + 1)) * IC;
                #pragma unroll
                for (int q = 0; q < 2; ++q) {
                    int ic = yq * 2 + q;       // 0..15
                    bf16x8 pk;
                    #pragma unroll
                    for (int j = 0; j < 8; ++j) {
                        float v = xp[(size_t)(ic * 8 + j) * (HH * WW)];
                        pk[j] = f2bf(v);
                    }
                    *(bf16x8*)(op + ic * 8) = pk;
                }
            }
        } else if (tid < 544) {
            // zero halo cols u=0 and u=57 of row v=h+1 (2 x 256 B)
            int t = tid - 512;
            int u = (t >> 4) * (XP - 1);
            *(f32x4*)((char*)(xb + ((size_t)(h + 1) * XP + u) * IC) + (t & 15) * 16) =
                (f32x4){0.f, 0.f, 0.f, 0.f};
        }
        // zero halo rows v=0 (by h==0 block) and v=57 (by h==55 block)
        if (h == 0 || h == HH - 1) {
            const int v = (h == 0) ? 0 : XP - 1;
            char* rowp = (char*)(xb + (size_t)v * XROW);
            for (int idx = tid; idx < XROW * 2 / 16; idx += 576)
                *(f32x4*)(rowp + idx * 16) = (f32x4){0.f, 0.f, 0.f, 0.f};
        }
        return;
    }

    // ---------------- head part (unchanged) ----------------
    __shared__ __align__(16) char Zl[32 * 1024];   // z bf16 swizzled, 32 KB
    __shared__ __align__(16) char Sl[144 * 64];    // result staging, 9216 B
    const int tid  = threadIdx.x;
    const int lane = tid & 63;
    const int wv   = tid >> 6;                     // 0..8

    if (tid < 256) {
        const int b = tid >> 3, ks = (tid & 7) * 64;
        const float* zp = z + (size_t)b * ZD + ks;
        const int bx = (b & 7) << 4;
        #pragma unroll
        for (int j8 = 0; j8 < 8; ++j8) {
            f32x4 v0 = *(const f32x4*)(zp + j8 * 8);
            f32x4 v1 = *(const f32x4*)(zp + j8 * 8 + 4);
            bf16x8 pk;
            pk[0] = f2bf_hw(v0.x); pk[1] = f2bf_hw(v0.y);
            pk[2] = f2bf_hw(v0.z); pk[3] = f2bf_hw(v0.w);
            pk[4] = f2bf_hw(v1.x); pk[5] = f2bf_hw(v1.y);
            pk[6] = f2bf_hw(v1.z); pk[7] = f2bf_hw(v1.w);
            *(bf16x8*)(Zl + b * 1024 + ((ks * 2 + j8 * 16) ^ bx)) = pk;
        }
    }
    __syncthreads();   // Zl ready

    const int rl = lane & 15;
    const int kq = lane >> 4;
    const int zxor = (rl & 7) << 4;
    const int rowLocal = wv * 16 + rl;   // 0..143
    const int rowg = blockIdx.x * 144 + rowLocal;

    const char* wp = (const char*)Wh + (size_t)rowg * (ZD * 4) + kq * 32;

    f32x4 wd[16];
    #pragma unroll
    for (int i = 0; i < 8; ++i) {
        wd[2 * i]     = *(const f32x4*)(wp + i * 128);
        wd[2 * i + 1] = *(const f32x4*)(wp + i * 128 + 16);
    }

    f32x4 acc0 = {0.f, 0.f, 0.f, 0.f}, acc1 = {0.f, 0.f, 0.f, 0.f};
    #pragma unroll
    for (int kb = 0; kb < 16; ++kb) {
        const int sl = kb & 7;
        const int koff = (kb * 64 + kq * 16) ^ zxor;
        bf16x8 a0 = *(const bf16x8*)(Zl + rl * 1024 + koff);
        bf16x8 a1 = *(const bf16x8*)(Zl + (16 + rl) * 1024 + koff);
        f32x4 lo = wd[2 * sl];
        f32x4 hi = wd[2 * sl + 1];
        bf16x8 bw;
        bw[0] = f2bf_hw(lo.x); bw[1] = f2bf_hw(lo.y);
        bw[2] = f2bf_hw(lo.z); bw[3] = f2bf_hw(lo.w);
        bw[4] = f2bf_hw(hi.x); bw[5] = f2bf_hw(hi.y);
        bw[6] = f2bf_hw(hi.z); bw[7] = f2bf_hw(hi.w);
        acc0 = __builtin_amdgcn_mfma_f32_16x16x32_bf16(a0, bw, acc0, 0, 0, 0);
        acc1 = __builtin_amdgcn_mfma_f32_16x16x32_bf16(a1, bw, acc1, 0, 0, 0);
        if (kb < 8) {
            wd[2 * sl]     = *(const f32x4*)(wp + (kb + 8) * 128);
            wd[2 * sl + 1] = *(const f32x4*)(wp + (kb + 8) * 128 + 16);
        }
    }

    {
        const int swz = (rowLocal & 7) << 3;
        s16x4 s0, s1;
        #pragma unroll
        for (int reg = 0; reg < 4; ++reg) {
            s0[reg] = f2bf(acc0[reg]);
            s1[reg] = f2bf(acc1[reg]);
        }
        *(s16x4*)(Sl + rowLocal * 64 + ((kq * 8) ^ swz))      = s0;
        *(s16x4*)(Sl + rowLocal * 64 + ((32 + kq * 8) ^ swz)) = s1;
    }
    __syncthreads();

    if (tid < 512) {
        const int b  = tid >> 4;
        const int oiL = tid & 15;
        const int oi = blockIdx.x * 16 + oiL;
        #pragma unroll
        for (int rs = 0; rs < 9; ++rs) {
            const int rowL = oiL * 9 + rs;
            short sh = *(const short*)(Sl + rowL * 64 +
                                       ((2 * b) ^ ((rowL & 7) << 3)));
            float v = bf2f(sh) + bh[(size_t)oi * 9 + rs];
            wbf[((size_t)(b * 9 + rs)) * OI + oi] = f2bf(v);
        }
    }
}

// ---------------------------------------------------------------------------
// Kernel 3 (v5): conv, BH=4, 256 thr = 4 waves (wave = output row hh),
// af=8 x pf=4 frags per wave (128o x 64p, 128 acc VGPR): per kk 12 ds_read
// for 32 MFMA (0.375 reads/MFMA vs v3's 0.5).  X [6][58][128] bf16 staged
// once from PADDED xtp (rows always in-bounds; only 3 KB halo-col zeroing).
// W double-buffered gll16 with counted vmcnt(8); 2 raw barriers/rs (dbuf
// reuse distance 1 needs the extra guard).  LDS 154 KB -> 1 blk/CU.
// ---------------------------------------------------------------------------
__global__ __launch_bounds__(256, 1) void conv_kernel(
    const short* __restrict__ wbf,   // [b][rs][o][i] bf16
    const short* __restrict__ xtp,   // [b][58][58][i] bf16, zero halo
    float* __restrict__ out)         // [b][o][h][w]  fp32
{
    __shared__ __align__(16) char Xl[6 * WDIM * 256];  // 89088 B
    __shared__ __align__(16) char Wl[2][32768];        // 65536 B
    const int tid  = threadIdx.x;
    const int lane = tid & 63;
    const int wv   = tid >> 6;       // 0..3 = output row hh
    const int h0 = blockIdx.x * 4;
    const int b  = blockIdx.y;
    const int rl = lane & 15;
    const int kq = lane >> 4;

    // zero halo cols u=0 / u=57 of the 6 tile rows (zeros are swizzle-invariant)
    if (tid < 192) {
        const int row = tid / 32;
        const int cp  = (tid >> 4) & 1;
        const int el  = tid & 15;
        const int u   = row * WDIM + cp * (WDIM - 1);
        *(f32x4*)(Xl + u * 256 + el * 16) = (f32x4){0.f, 0.f, 0.f, 0.f};
    }
    __syncthreads();   // halo zeros visible; no VMEM outstanding yet

    // stage X rows 0..5 from padded xtp (v = h0+rr, always in-bounds), cols 1..56
    const short* xb = xtp + (size_t)b * XBAT;
    for (int rr = 0; rr < 6; ++rr) {
        const char* src = (const char*)(xb + (size_t)(h0 + rr) * XROW + IC);
        char* dstb = Xl + (rr * WDIM + 1) * 256;
        for (int it = wv; it < 14; it += 4) {
            int c = it * 64 + lane;
            int u = rr * WDIM + 1 + (c >> 4);
            int soff = (c * 16) ^ ((u & 7) << 4);
            gll16(src + soff, dstb + it * 1024);
        }
    }

    // W staging: 8 gll16 per wave per slice (wave-uniform count)
    #define STAGE_CW(rs_, buf_)                                                 \
        {                                                                       \
            const char* ws_ = (const char*)(wbf +                               \
                ((size_t)b * NRS + (rs_)) * OI);                                \
            _Pragma("unroll")                                                   \
            for (int it_ = 0; it_ < 8; ++it_) {                                 \
                int c_ = (wv * 8 + it_) * 64 + lane;                            \
                int so_ = (c_ * 16) ^ (((c_ >> 4) & 7) << 4);                   \
                gll16(ws_ + so_, Wl[buf_] + (wv * 8 + it_) * 1024);             \
            }                                                                   \
        }

    STAGE_CW(0, 0);

    f32x4 acc[8][4];   // [af][pf]
    #pragma unroll
    for (int a = 0; a < 8; ++a)
        #pragma unroll
        for (int p = 0; p < 4; ++p) acc[a][p] = (f32x4){0.f, 0.f, 0.f, 0.f};

    const int axor = (lane & 7) << 4;
    int kkoff[4];
    #pragma unroll
    for (int kk = 0; kk < 4; ++kk) kkoff[kk] = kk * 64 + (kq << 4);

    for (int rs = 0; rs < 9; ++rs) {
        // barrier #1: all waves finished reading buf (rs+1)&1 (used at rs-1)
        __builtin_amdgcn_s_barrier();
        __builtin_amdgcn_sched_barrier(0);
        if (rs < 8) STAGE_CW(rs + 1, (rs + 1) & 1);
        if (rs == 8) { asm volatile("s_waitcnt vmcnt(0)" ::: "memory"); }
        else         { asm volatile("s_waitcnt vmcnt(8)" ::: "memory"); }
        __builtin_amdgcn_sched_barrier(0);
        __builtin_amdgcn_s_barrier();   // #2: stage(rs) (and X, first iter) visible
        __builtin_amdgcn_sched_barrier(0);

        const char* Wb = Wl[rs & 1];
        const int r = rs / 3, s = rs - 3 * r;
        int ubase[4], bswz[4];
        #pragma unroll
        for (int pf = 0; pf < 4; ++pf) {
            int p = pf * 16 + rl;
            int pc = p > 55 ? 55 : p;            // clamp garbage lanes
            int uu = (wv + r) * WDIM + pc + s;   // tile row = hh + r
            ubase[pf] = uu * 256;
            bswz[pf] = (uu & 7) << 4;
        }
        #pragma unroll
        for (int kk = 0; kk < 4; ++kk) {
            bf16x8 av[8];
            #pragma unroll
            for (int af = 0; af < 8; ++af)
                av[af] = *(const bf16x8*)(Wb + (af * 16 + rl) * 256 +
                                          (kkoff[kk] ^ axor));
            #pragma unroll
            for (int pf = 0; pf < 4; ++pf) {
                bf16x8 bv = *(const bf16x8*)(Xl + ubase[pf] + (kkoff[kk] ^ bswz[pf]));
                #pragma unroll
                for (int af = 0; af < 8; ++af)
                    acc[af][pf] = __builtin_amdgcn_mfma_f32_16x16x32_bf16(
                        av[af], bv, acc[af][pf], 0, 0, 0);
            }
        }
    }
    #undef STAGE_CW

    // epilogue: D col = rl (=p), row = 4*kq+reg (=o offset)
    const int hO = h0 + wv;
    #pragma unroll
    for (int af = 0; af < 8; ++af) {
        int o0 = af * 16 + kq * 4;
        #pragma unroll
        for (int pf = 0; pf < 4; ++pf) {
            int p = pf * 16 + rl;
            if (p < WW) {
                #pragma unroll
                for (int reg = 0; reg < 4; ++reg) {
                    out[(((size_t)b * OC + (o0 + reg)) * HH + hO) * WW + p] = acc[af][pf][reg];
                }
            }
        }
    }
}

extern "C" void kernel_launch(void* const* d_in, const int* in_sizes, int n_in,
                              void* d_out, int out_size, void* d_ws, size_t ws_size,
                              hipStream_t stream) {
    const float* x  = (const float*)d_in[0];   // [32,128,56,56]
    const float* z  = (const float*)d_in[1];   // [32,512]
    const float* Wh = (const float*)d_in[2];   // [147456,512]
    const float* bh = (const float*)d_in[3];   // [147456]
    float* out = (float*)d_out;

    short* wbf = (short*)d_ws;                               // 9,437,184 B
    short* xtp = (short*)((char*)d_ws + 9437184);            // 27,557,888 B

    fused_head_tr_kernel<<<dim3(NHEADBLK + NTRBLK), 576, 0, stream>>>(Wh, z, bh, wbf, x, xtp);
    conv_kernel<<<dim3(HH / 4, BB), 256, 0, stream>>>(wbf, xtp, out);
}